// Round 17
// baseline (234.029 us; speedup 1.0000x reference)
//
#include <hip/hip_runtime.h>
#include <hip/hip_fp16.h>

#define N_NODES 100000
#define N_EDGES 1600000
#define NCLS 40
#define NBUCK 196          // buckets of 512 nodes; bucket = id >> 9
#define CAPE 8960          // per-bucket edge capacity
#define CAPC 10752         // per-bucket CSR capacity incl. x8 padding
#define DUMMY N_NODES      // pad source id; packed w bits = 0 -> exact no-op

typedef unsigned short u16;
typedef unsigned int u32;
typedef short bf16x8 __attribute__((ext_vector_type(8)));
typedef float f32x4 __attribute__((ext_vector_type(4)));

static inline size_t align256(size_t x) { return (x + 255) & ~(size_t)255; }

__device__ __forceinline__ float bf2f(u16 h) { return __uint_as_float(((u32)h) << 16); }
__device__ __forceinline__ u16 f2bf(float f) {
    u32 u = __float_as_uint(f);
    u += 0x7FFFu + ((u >> 16) & 1u);  // round-to-nearest-even
    return (u16)(u >> 16);
}
__device__ __forceinline__ u32 pk2(u16 a, u16 b) { return (u32)a | ((u32)b << 16); }
__device__ __forceinline__ u32 pack15(float f) {   // positive fp16 sans sign bit
    return ((u32)__half_as_ushort(__float2half(f))) & 0x7FFFu;
}
__device__ __forceinline__ float unpack15(u32 bits) {
    return __half2float(__ushort_as_half((u16)bits));
}
__device__ __forceinline__ float blo(u32 v) { return __uint_as_float(v << 16); }
__device__ __forceinline__ float bhi(u32 v) { return __uint_as_float(v & 0xFFFF0000u); }

// ---------- pass 1: LDS-histogram partition by bucket + fused x->bf16 ----------
#define PS_BLOCKS 391
#define CONV_BLOCKS 6250

__global__ __launch_bounds__(256) void pscatter_conv(const int* __restrict__ src,
                                                     const int* __restrict__ dst,
                                                     int* __restrict__ gFillD,
                                                     int* __restrict__ gFillS,
                                                     u32* __restrict__ partD,
                                                     u16* __restrict__ partS,
                                                     const float* __restrict__ x,
                                                     u16* __restrict__ xb) {
    if (blockIdx.x >= PS_BLOCKS) {
        int i = (blockIdx.x - PS_BLOCKS) * 256 + threadIdx.x;  // 4 floats/thread
        float4 v = *(const float4*)(x + (size_t)i * 4);
        ushort4 o;
        o.x = f2bf(v.x); o.y = f2bf(v.y); o.z = f2bf(v.z); o.w = f2bf(v.w);
        *(ushort4*)(xb + (size_t)i * 4) = o;
        return;
    }
    __shared__ int histD[NBUCK], histS[NBUCK], chunkD[NBUCK], chunkS[NBUCK];
    int tid = threadIdx.x;
    int base = blockIdx.x * 4096;

    int4 sv[4], dv[4];
#pragma unroll
    for (int j = 0; j < 4; ++j) {
        int idx = base + j * 1024 + tid * 4;
        if (idx < N_EDGES) {
            sv[j] = *(const int4*)(src + idx);
            dv[j] = *(const int4*)(dst + idx);
        } else {
            sv[j] = make_int4(0, 0, 0, 0);
            dv[j] = make_int4(0, 0, 0, 0);
        }
    }

    for (int i = tid; i < NBUCK; i += 256) { histD[i] = 0; histS[i] = 0; }
    __syncthreads();
#pragma unroll
    for (int j = 0; j < 4; ++j)
#pragma unroll
        for (int k = 0; k < 4; ++k) {
            int s = ((const int*)&sv[j])[k], d = ((const int*)&dv[j])[k];
            if (s != d) {
                atomicAdd(&histD[d >> 9], 1);
                atomicAdd(&histS[s >> 9], 1);
            }
        }
    __syncthreads();
    for (int B = tid; B < NBUCK; B += 256) {
        int cD = histD[B];
        chunkD[B] = cD ? atomicAdd(&gFillD[B], cD) : 0;
        int cS = histS[B];
        chunkS[B] = cS ? atomicAdd(&gFillS[B], cS) : 0;
    }
    __syncthreads();
    for (int i = tid; i < NBUCK; i += 256) { histD[i] = 0; histS[i] = 0; }
    __syncthreads();
#pragma unroll
    for (int j = 0; j < 4; ++j)
#pragma unroll
        for (int k = 0; k < 4; ++k) {
            int s = ((const int*)&sv[j])[k], d = ((const int*)&dv[j])[k];
            if (s != d) {
                int bD = d >> 9;
                int r = atomicAdd(&histD[bD], 1);
                int o = chunkD[bD] + r;
                if (o < CAPE) partD[bD * CAPE + o] = ((u32)s << 9) | (u32)(d & 511);
                int bS = s >> 9;
                int r2 = atomicAdd(&histS[bS], 1);
                int o2 = chunkS[bS] + r2;
                if (o2 < CAPE) partS[bS * CAPE + o2] = (u16)(s & 511);
            }
        }
}

// ---------- pass 2a: src-side out-degree histogram -> dis ----------
__global__ __launch_bounds__(256) void build_dis(const u16* __restrict__ partS,
                                                 const int* __restrict__ gFillS,
                                                 float* __restrict__ dis) {
    __shared__ int cnt[512];
    int tid = threadIdx.x;
    int B = blockIdx.x;
    for (int i = tid; i < 512; i += 256) cnt[i] = 0;
    __syncthreads();
    int nS = min(gFillS[B], CAPE);
    for (int i = tid; i < nS; i += 256) atomicAdd(&cnt[partS[B * CAPE + i]], 1);
    __syncthreads();
    for (int n = tid; n < 512; n += 256) {
        int node = B * 512 + n;
        if (node < N_NODES) {
            int dg = cnt[n];
            dis[node] = dg > 0 ? 1.0f / sqrtf((float)dg) : 0.0f;
        }
    }
}

// ---------- pass 2b: CSR build; entry = src | fp15(dis[src])<<17; + degree-bin histogram ----------
__global__ __launch_bounds__(256) void build_csr(const u32* __restrict__ partD,
                                                 const int* __restrict__ gFillD,
                                                 const float* __restrict__ dis,
                                                 u32* __restrict__ csr,
                                                 int2* __restrict__ meta,
                                                 int* __restrict__ binCnt) {
    __shared__ int cnt[512], loc[512], rnk[512];
    __shared__ int binh[8];
    int tid = threadIdx.x;
    int B = blockIdx.x;
    if (tid < 8) binh[tid] = 0;
    for (int i = tid; i < 512; i += 256) { cnt[i] = 0; rnk[i] = 0; }
    __syncthreads();
    int nD = min(gFillD[B], CAPE);
    for (int i = tid; i < nD; i += 256) atomicAdd(&cnt[partD[B * CAPE + i] & 511], 1);
    __syncthreads();
    if (tid < 64) {
        int bb = tid * 8, c8[8], mysum = 0;
#pragma unroll
        for (int j = 0; j < 8; ++j) { c8[j] = (cnt[bb + j] + 7) & ~7; mysum += c8[j]; }
        int incl = mysum;
#pragma unroll
        for (int off = 1; off < 64; off <<= 1) {
            int v = __shfl_up(incl, off);
            if (tid >= off) incl += v;
        }
        int run = incl - mysum;
#pragma unroll
        for (int j = 0; j < 8; ++j) { loc[bb + j] = run; run += c8[j]; }
    }
    __syncthreads();
    for (int n = tid; n < 512; n += 256) {
        int node = B * 512 + n;
        if (node < N_NODES) {
            int c = cnt[n], c8 = (c + 7) & ~7;
            meta[node] = make_int2(B * CAPC + loc[n], c);
            for (int e = c; e < c8; ++e) csr[B * CAPC + loc[n] + e] = (u32)DUMMY;
            atomicAdd(&binh[min(c8 >> 3, 7)], 1);
        }
    }
    for (int i = tid; i < nD; i += 256) {
        u32 p = partD[B * CAPE + i];
        int ln = p & 511;
        u32 s = p >> 9;
        int r = atomicAdd(&rnk[ln], 1);
        int pos = loc[ln] + r;
        if (pos < CAPC) csr[B * CAPC + pos] = s | (pack15(dis[s]) << 17);
    }
    __syncthreads();
    if (tid < 8 && binh[tid] > 0) atomicAdd(&binCnt[tid], binh[tid]);
}

// ---------- pass 2c: 8-bin exclusive prefix ----------
__global__ void prefix8(const int* __restrict__ binCnt, int* __restrict__ binBase) {
    if (threadIdx.x == 0) {
        int run = 0;
        for (int b = 0; b < 8; ++b) { binBase[b] = run; run += binCnt[b]; }
    }
}

// ---------- pass 2d: degree-bin-sorted node order (waves become degree-uniform) ----------
__global__ __launch_bounds__(256) void order_scatter(const int2* __restrict__ meta,
                                                     const int* __restrict__ binBase,
                                                     int* __restrict__ binFill,
                                                     int* __restrict__ order) {
    __shared__ int lcnt[8], chunk[8], lrank[8];
    int tid = threadIdx.x, B = blockIdx.x;
    if (tid < 8) { lcnt[tid] = 0; lrank[tid] = 0; }
    __syncthreads();
    int bins[2];
#pragma unroll
    for (int k = 0; k < 2; ++k) {
        int node = B * 512 + tid + k * 256;
        if (node < N_NODES) {
            int c8 = (meta[node].y + 7) & ~7;
            int b = min(c8 >> 3, 7);
            bins[k] = b;
            atomicAdd(&lcnt[b], 1);
        } else bins[k] = -1;
    }
    __syncthreads();
    if (tid < 8) chunk[tid] = lcnt[tid] ? atomicAdd(&binFill[tid], lcnt[tid]) : 0;
    __syncthreads();
#pragma unroll
    for (int k = 0; k < 2; ++k) {
        if (bins[k] >= 0) {
            int node = B * 512 + tid + k * 256;
            int r = atomicAdd(&lrank[bins[k]], 1);
            order[binBase[bins[k]] + chunk[bins[k]] + r] = node;
        }
    }
}

// ---------- SPMM gather: 8 nodes/wave (degree-binned), 8 lanes/node, dwordx4 rows ----------
template <int J>
__device__ __forceinline__ void edge_step(u32 ent, const uint4* __restrict__ in4,
                                          int p, float* a) {
    u32 q = (u32)__builtin_amdgcn_ds_swizzle((int)ent, (J << 5) | 0x18);
    u32 s = q & 0x1FFFFu;
    float w = unpack15(q >> 17);           // pad entries: w bits = 0 -> exact no-op
    uint4 v = in4[((size_t)s << 3) + p];
    a[0] = fmaf(w, blo(v.x), a[0]);
    a[1] = fmaf(w, bhi(v.x), a[1]);
    a[2] = fmaf(w, blo(v.y), a[2]);
    a[3] = fmaf(w, bhi(v.y), a[3]);
    a[4] = fmaf(w, blo(v.z), a[4]);
    a[5] = fmaf(w, bhi(v.z), a[5]);
    a[6] = fmaf(w, blo(v.w), a[6]);
    a[7] = fmaf(w, bhi(v.w), a[7]);
}

#define SPMM_BLOCKS 3125   // 3125 blocks * 4 waves * 8 nodes = 100000 exactly

__global__ __launch_bounds__(256) void spmm(const u16* __restrict__ in,     // (N+1)x64 bf16
                                            const float* __restrict__ dis,
                                            const int2* __restrict__ meta,
                                            const u32* __restrict__ csr,
                                            const int* __restrict__ order,
                                            u16* __restrict__ outhi) {
    const int tid = threadIdx.x;
    const int lane = tid & 63;
    const int gw = blockIdx.x * 4 + (tid >> 6);   // global wave id
    const int slot = gw * 8 + (lane >> 3);        // degree-binned slot
    const int node = order[slot];
    const int p = lane & 7;                        // feature chunk [8p, 8p+8)

    int2 mt = meta[node];
    int c8 = (mt.y + 7) & ~7;                      // list DUMMY-padded to x8
    const u32* lst = csr + mt.x;
    const uint4* in4 = (const uint4*)in;

    float a[8] = {0.f, 0.f, 0.f, 0.f, 0.f, 0.f, 0.f, 0.f};

    for (int e = 0; e < c8; e += 8) {
        u32 ent = lst[e + p];                      // lane p holds group's entry e+p
        edge_step<0>(ent, in4, p, a);
        edge_step<1>(ent, in4, p, a);
        edge_step<2>(ent, in4, p, a);
        edge_step<3>(ent, in4, p, a);
        edge_step<4>(ent, in4, p, a);
        edge_step<5>(ent, in4, p, a);
        edge_step<6>(ent, in4, p, a);
        edge_step<7>(ent, in4, p, a);
    }

    float vd = -dis[node];
    uint4 H;
    H.x = pk2(f2bf(vd * a[0]), f2bf(vd * a[1]));
    H.y = pk2(f2bf(vd * a[2]), f2bf(vd * a[3]));
    H.z = pk2(f2bf(vd * a[4]), f2bf(vd * a[5]));
    H.w = pk2(f2bf(vd * a[6]), f2bf(vd * a[7]));
    *((uint4*)((u32*)outhi + (((size_t)node << 5) + (p << 2)))) = H;
}

// ---------- dense via MFMA, split-bf16 A0 only, Chebyshev fold in the weights ----------
// out = A0@(W0 - W2) + A1@W1 + Ty@(2*W2);  A1/Ty bf16-only, A0 keeps a lo plane.
#define DGRID 1250
#define DNT 5              // 1250 * 5 * 16 = 100000 rows exactly
#define LSTR 200           // u16 per LDS row for Ah (192 data + 8 pad)
#define LSTR2 72           // u16 per LDS row for Al (64 data + 8 pad)

__device__ __forceinline__ float foldW(const float* __restrict__ W, int kk, int col,
                                       int ncols) {
    float wv = W[kk * ncols + col];
    if (kk < 64) wv -= W[(kk + 128) * ncols + col];   // W0 - W2
    else if (kk >= 128) wv += wv;                     // 2 * W2
    return wv;
}

__global__ __launch_bounds__(256) void dense1_mf(const float* __restrict__ x,
                                                 const u16* __restrict__ a1h,
                                                 const u16* __restrict__ tyh,
                                                 const float* __restrict__ W,
                                                 const float* __restrict__ bias,
                                                 u16* __restrict__ ohi,
                                                 u16* __restrict__ olo) {
    __shared__ u16 Ah[16 * LSTR], Al[16 * LSTR2];
    const int tid = threadIdx.x, wid = tid >> 6, lane = tid & 63;
    const int lrow = lane & 15, lk8 = (lane >> 4) * 8;
    const int col = wid * 16 + lrow;

    bf16x8 wh[6], wl[6];
#pragma unroll
    for (int c = 0; c < 6; ++c) {
        bf16x8 h, l;
#pragma unroll
        for (int i = 0; i < 8; ++i) {
            float wv = foldW(W, c * 32 + lk8 + i, col, 64);
            u16 hb_ = f2bf(wv);
            h[i] = (short)hb_;
            l[i] = (short)f2bf(wv - bf2f(hb_));
        }
        wh[c] = h; wl[c] = l;
    }
    float bv = bias[col];
    const int srow = tid >> 4, sc4 = (tid & 15) * 4;

    for (int t = 0; t < DNT; ++t) {
        int r0 = (blockIdx.x * DNT + t) * 16;
        size_t rb = ((size_t)(r0 + srow) << 6) + sc4;
        {
            float4 v = *(const float4*)&x[rb];
            const float* vp = (const float*)&v;
            ushort4 hv, lv;
#pragma unroll
            for (int i = 0; i < 4; ++i) {
                u16 hb_ = f2bf(vp[i]);
                ((u16*)&hv)[i] = hb_;
                ((u16*)&lv)[i] = f2bf(vp[i] - bf2f(hb_));
            }
            *(ushort4*)&Ah[srow * LSTR + sc4] = hv;
            *(ushort4*)&Al[srow * LSTR2 + sc4] = lv;
        }
        *(ushort4*)&Ah[srow * LSTR + 64 + sc4] = *(const ushort4*)&a1h[rb];
        *(ushort4*)&Ah[srow * LSTR + 128 + sc4] = *(const ushort4*)&tyh[rb];
        __syncthreads();

        f32x4 acc = {bv, bv, bv, bv};
#pragma unroll
        for (int c = 0; c < 6; ++c) {
            bf16x8 ah = *(const bf16x8*)&Ah[lrow * LSTR + c * 32 + lk8];
            acc = __builtin_amdgcn_mfma_f32_16x16x32_bf16(ah, wh[c], acc, 0, 0, 0);
            acc = __builtin_amdgcn_mfma_f32_16x16x32_bf16(ah, wl[c], acc, 0, 0, 0);
        }
#pragma unroll
        for (int c = 0; c < 2; ++c) {   // A0 lo plane covers k in [0,64)
            bf16x8 al = *(const bf16x8*)&Al[lrow * LSTR2 + c * 32 + lk8];
            acc = __builtin_amdgcn_mfma_f32_16x16x32_bf16(al, wh[c], acc, 0, 0, 0);
        }
        __syncthreads();

#pragma unroll
        for (int j = 0; j < 4; ++j) {
            int row = r0 + (lane >> 4) * 4 + j;
            float v = fmaxf(acc[j], 0.0f);
            u16 hb_ = f2bf(v);
            ohi[((size_t)row << 6) + col] = hb_;
            olo[((size_t)row << 6) + col] = f2bf(v - bf2f(hb_));
        }
    }
}

__global__ __launch_bounds__(256) void dense2_mf(const u16* __restrict__ a0h,
                                                 const u16* __restrict__ a0l,
                                                 const u16* __restrict__ a1h,
                                                 const u16* __restrict__ tyh,
                                                 const float* __restrict__ W,
                                                 const float* __restrict__ bias,
                                                 float* __restrict__ out) {
    __shared__ u16 Ah[16 * LSTR], Al[16 * LSTR2];
    __shared__ float Ls[16][48];
    const int tid = threadIdx.x, wid = tid >> 6, lane = tid & 63;
    const int lrow = lane & 15, lk8 = (lane >> 4) * 8;
    const int col = wid * 16 + lrow;
    const bool act = (wid < 3);
    const bool cok = act && (col < NCLS);

    bf16x8 wh[6], wl[6];
#pragma unroll
    for (int c = 0; c < 6; ++c) {
        bf16x8 h = 0, l = 0;
        if (cok) {
#pragma unroll
            for (int i = 0; i < 8; ++i) {
                float wv = foldW(W, c * 32 + lk8 + i, col, NCLS);
                u16 hb_ = f2bf(wv);
                h[i] = (short)hb_;
                l[i] = (short)f2bf(wv - bf2f(hb_));
            }
        }
        wh[c] = h; wl[c] = l;
    }
    float bv = cok ? bias[col] : 0.0f;
    const int srow = tid >> 4, sc4 = (tid & 15) * 4;

    for (int t = 0; t < DNT; ++t) {
        int r0 = (blockIdx.x * DNT + t) * 16;
        size_t rb = ((size_t)(r0 + srow) << 6) + sc4;
        *(ushort4*)&Ah[srow * LSTR + sc4] = *(const ushort4*)&a0h[rb];
        *(ushort4*)&Al[srow * LSTR2 + sc4] = *(const ushort4*)&a0l[rb];
        *(ushort4*)&Ah[srow * LSTR + 64 + sc4] = *(const ushort4*)&a1h[rb];
        *(ushort4*)&Ah[srow * LSTR + 128 + sc4] = *(const ushort4*)&tyh[rb];
        __syncthreads();

        if (act) {
            f32x4 acc = {bv, bv, bv, bv};
#pragma unroll
            for (int c = 0; c < 6; ++c) {
                bf16x8 ah = *(const bf16x8*)&Ah[lrow * LSTR + c * 32 + lk8];
                acc = __builtin_amdgcn_mfma_f32_16x16x32_bf16(ah, wh[c], acc, 0, 0, 0);
                acc = __builtin_amdgcn_mfma_f32_16x16x32_bf16(ah, wl[c], acc, 0, 0, 0);
            }
#pragma unroll
            for (int c = 0; c < 2; ++c) {
                bf16x8 al = *(const bf16x8*)&Al[lrow * LSTR2 + c * 32 + lk8];
                acc = __builtin_amdgcn_mfma_f32_16x16x32_bf16(al, wh[c], acc, 0, 0, 0);
            }
#pragma unroll
            for (int j = 0; j < 4; ++j) Ls[(lane >> 4) * 4 + j][col] = acc[j];
        }
        __syncthreads();

        {   // softmax: 16 rows, one 16-lane group per row (4 rows per wave)
            int row = wid * 4 + (lane >> 4);
            int cg = lane & 15;
            float v0 = Ls[row][cg];
            float v1 = Ls[row][cg + 16];
            float v2 = (cg < 8) ? Ls[row][cg + 32] : -1e30f;
            float m = fmaxf(fmaxf(v0, v1), v2);
#pragma unroll
            for (int o = 8; o; o >>= 1) m = fmaxf(m, __shfl_xor(m, o));
            float e0 = expf(v0 - m), e1 = expf(v1 - m);
            float e2 = (cg < 8) ? expf(v2 - m) : 0.0f;
            float s = e0 + e1 + e2;
#pragma unroll
            for (int o = 8; o; o >>= 1) s += __shfl_xor(s, o);
            float inv = 1.0f / s;
            size_t ob = (size_t)(r0 + row) * NCLS;
            out[ob + cg] = e0 * inv;
            out[ob + cg + 16] = e1 * inv;
            if (cg < 8) out[ob + cg + 32] = e2 * inv;
        }
    }
}

// ---------------- host ----------------

extern "C" void kernel_launch(void* const* d_in, const int* in_sizes, int n_in,
                              void* d_out, int out_size, void* d_ws, size_t ws_size,
                              hipStream_t stream) {
    const float* x = (const float*)d_in[0];
    const int* edge_index = (const int*)d_in[1];
    const float* W1 = (const float*)d_in[2];
    const float* b1 = (const float*)d_in[3];
    const float* W2 = (const float*)d_in[4];
    const float* b2 = (const float*)d_in[5];
    float* out = (float*)d_out;

    const int* src = edge_index;
    const int* dst = edge_index + N_EDGES;

    char* ws = (char*)d_ws;
    size_t off = 0;
    auto carve = [&](size_t bytes) -> void* {
        void* p = ws + off;
        off = align256(off + bytes);
        return p;
    };
    int* gFillD = (int*)carve((size_t)NBUCK * 4);
    int* gFillS = (int*)carve((size_t)NBUCK * 4);
    int* binCnt = (int*)carve(8 * 4);
    int* binFill = (int*)carve(8 * 4);
    size_t zero_bytes = off;
    int* binBase = (int*)carve(8 * 4);
    int* order = (int*)carve((size_t)N_NODES * 4);          // 0.4 MB
    u32* partD = (u32*)carve((size_t)NBUCK * CAPE * 4);     // 7.0 MB ((s<<9)|dlocal)
    u16* partS = (u16*)carve((size_t)NBUCK * CAPE * 2);     // 3.5 MB (bucket-local src)
    u32* csr = (u32*)carve((size_t)NBUCK * CAPC * 4 + 1024);// 8.4 MB (src|w15<<17)
    int2* meta = (int2*)carve((size_t)N_NODES * 8);         // 0.8 MB
    float* dis = (float*)carve((size_t)(N_NODES + 1) * 4);  // 0.4 MB
    const size_t FB = (size_t)(N_NODES + 1) * 64 * 2;       // 12.8 MB per bf16 plane
    u16* xb  = (u16*)carve(FB);
    u16* t1h = (u16*)carve(FB);   // Tx1 / Th1 hi (bf16-only)
    u16* tyh = (u16*)carve(FB);   // L.Tx1 / L.Th1 hi (bf16-only)
    u16* hh  = (u16*)carve(FB);   // h hi (gather input for layer 2)
    u16* hl  = (u16*)carve(FB);   // h lo (dense2 A0 lo plane)
    // total ~85 MB

    (void)hipMemsetAsync(d_ws, 0, zero_bytes, stream);   // gFill/binCnt/binFill (~1.7 KB)

    pscatter_conv<<<PS_BLOCKS + CONV_BLOCKS, 256, 0, stream>>>(src, dst, gFillD, gFillS,
                                                               partD, partS, x, xb);
    build_dis<<<NBUCK, 256, 0, stream>>>(partS, gFillS, dis);
    build_csr<<<NBUCK, 256, 0, stream>>>(partD, gFillD, dis, csr, meta, binCnt);
    prefix8<<<1, 64, 0, stream>>>(binCnt, binBase);
    order_scatter<<<NBUCK, 256, 0, stream>>>(meta, binBase, binFill, order);

    // layer 1: Tx1 = L.x ; Ty = L.Tx1 ; h = relu(x@(W0-W2) + Tx1@W1 + Ty@2W2 + b1)
    spmm<<<SPMM_BLOCKS, 256, 0, stream>>>(xb, dis, meta, csr, order, t1h);
    spmm<<<SPMM_BLOCKS, 256, 0, stream>>>(t1h, dis, meta, csr, order, tyh);
    dense1_mf<<<DGRID, 256, 0, stream>>>(x, t1h, tyh, W1, b1, hh, hl);

    // layer 2 (t1h/tyh reused)
    spmm<<<SPMM_BLOCKS, 256, 0, stream>>>(hh, dis, meta, csr, order, t1h);
    spmm<<<SPMM_BLOCKS, 256, 0, stream>>>(t1h, dis, meta, csr, order, tyh);
    dense2_mf<<<DGRID, 256, 0, stream>>>(hh, hl, t1h, tyh, W2, b2, out);
}

// Round 18
// 222.744 us; speedup vs baseline: 1.0507x; 1.0507x over previous
//
#include <hip/hip_runtime.h>
#include <hip/hip_fp16.h>

#define N_NODES 100000
#define N_EDGES 1600000
#define NCLS 40
#define NBUCK 196          // buckets of 512 nodes; bucket = id >> 9
#define CAPE 8960          // per-bucket edge capacity
#define CAPC 10752         // per-bucket CSR capacity incl. x8 padding
#define DUMMY N_NODES      // pad source id; packed w bits = 0 -> exact no-op

typedef unsigned short u16;
typedef unsigned int u32;
typedef short bf16x8 __attribute__((ext_vector_type(8)));
typedef float f32x4 __attribute__((ext_vector_type(4)));

static inline size_t align256(size_t x) { return (x + 255) & ~(size_t)255; }

__device__ __forceinline__ float bf2f(u16 h) { return __uint_as_float(((u32)h) << 16); }
__device__ __forceinline__ u16 f2bf(float f) {
    u32 u = __float_as_uint(f);
    u += 0x7FFFu + ((u >> 16) & 1u);  // round-to-nearest-even
    return (u16)(u >> 16);
}
__device__ __forceinline__ u32 pk2(u16 a, u16 b) { return (u32)a | ((u32)b << 16); }
__device__ __forceinline__ u32 pack15(float f) {   // positive fp16 sans sign bit
    return ((u32)__half_as_ushort(__float2half(f))) & 0x7FFFu;
}
__device__ __forceinline__ float unpack15(u32 bits) {
    return __half2float(__ushort_as_half((u16)bits));
}
__device__ __forceinline__ float blo(u32 v) { return __uint_as_float(v << 16); }
__device__ __forceinline__ float bhi(u32 v) { return __uint_as_float(v & 0xFFFF0000u); }

// ---------- pass 1: LDS-histogram partition by bucket + fused x->bf16 ----------
#define PS_BLOCKS 391
#define CONV_BLOCKS 6250

__global__ __launch_bounds__(256) void pscatter_conv(const int* __restrict__ src,
                                                     const int* __restrict__ dst,
                                                     int* __restrict__ gFillD,
                                                     int* __restrict__ gFillS,
                                                     u32* __restrict__ partD,
                                                     u16* __restrict__ partS,
                                                     const float* __restrict__ x,
                                                     u16* __restrict__ xb) {
    if (blockIdx.x >= PS_BLOCKS) {
        int i = (blockIdx.x - PS_BLOCKS) * 256 + threadIdx.x;  // 4 floats/thread
        float4 v = *(const float4*)(x + (size_t)i * 4);
        ushort4 o;
        o.x = f2bf(v.x); o.y = f2bf(v.y); o.z = f2bf(v.z); o.w = f2bf(v.w);
        *(ushort4*)(xb + (size_t)i * 4) = o;
        return;
    }
    __shared__ int histD[NBUCK], histS[NBUCK], chunkD[NBUCK], chunkS[NBUCK];
    int tid = threadIdx.x;
    int base = blockIdx.x * 4096;

    int4 sv[4], dv[4];
#pragma unroll
    for (int j = 0; j < 4; ++j) {
        int idx = base + j * 1024 + tid * 4;
        if (idx < N_EDGES) {
            sv[j] = *(const int4*)(src + idx);
            dv[j] = *(const int4*)(dst + idx);
        } else {
            sv[j] = make_int4(0, 0, 0, 0);
            dv[j] = make_int4(0, 0, 0, 0);
        }
    }

    for (int i = tid; i < NBUCK; i += 256) { histD[i] = 0; histS[i] = 0; }
    __syncthreads();
#pragma unroll
    for (int j = 0; j < 4; ++j)
#pragma unroll
        for (int k = 0; k < 4; ++k) {
            int s = ((const int*)&sv[j])[k], d = ((const int*)&dv[j])[k];
            if (s != d) {
                atomicAdd(&histD[d >> 9], 1);
                atomicAdd(&histS[s >> 9], 1);
            }
        }
    __syncthreads();
    for (int B = tid; B < NBUCK; B += 256) {
        int cD = histD[B];
        chunkD[B] = cD ? atomicAdd(&gFillD[B], cD) : 0;
        int cS = histS[B];
        chunkS[B] = cS ? atomicAdd(&gFillS[B], cS) : 0;
    }
    __syncthreads();
    for (int i = tid; i < NBUCK; i += 256) { histD[i] = 0; histS[i] = 0; }
    __syncthreads();
#pragma unroll
    for (int j = 0; j < 4; ++j)
#pragma unroll
        for (int k = 0; k < 4; ++k) {
            int s = ((const int*)&sv[j])[k], d = ((const int*)&dv[j])[k];
            if (s != d) {
                int bD = d >> 9;
                int r = atomicAdd(&histD[bD], 1);
                int o = chunkD[bD] + r;
                if (o < CAPE) partD[bD * CAPE + o] = ((u32)s << 9) | (u32)(d & 511);
                int bS = s >> 9;
                int r2 = atomicAdd(&histS[bS], 1);
                int o2 = chunkS[bS] + r2;
                if (o2 < CAPE) partS[bS * CAPE + o2] = (u16)(s & 511);
            }
        }
}

// ---------- pass 2a: src-side out-degree histogram -> dis ----------
__global__ __launch_bounds__(256) void build_dis(const u16* __restrict__ partS,
                                                 const int* __restrict__ gFillS,
                                                 float* __restrict__ dis) {
    __shared__ int cnt[512];
    int tid = threadIdx.x;
    int B = blockIdx.x;
    for (int i = tid; i < 512; i += 256) cnt[i] = 0;
    __syncthreads();
    int nS = min(gFillS[B], CAPE);
    for (int i = tid; i < nS; i += 256) atomicAdd(&cnt[partS[B * CAPE + i]], 1);
    __syncthreads();
    for (int n = tid; n < 512; n += 256) {
        int node = B * 512 + n;
        if (node < N_NODES) {
            int dg = cnt[n];
            dis[node] = dg > 0 ? 1.0f / sqrtf((float)dg) : 0.0f;
        }
    }
}

// ---------- pass 2b: CSR build (plain rank order); entry = src | fp15(dis[src])<<17 ----------
__global__ __launch_bounds__(256) void build_csr(const u32* __restrict__ partD,
                                                 const int* __restrict__ gFillD,
                                                 const float* __restrict__ dis,
                                                 u32* __restrict__ csr,
                                                 int2* __restrict__ meta) {
    __shared__ int cnt[512], loc[512], rnk[512];
    int tid = threadIdx.x;
    int B = blockIdx.x;
    for (int i = tid; i < 512; i += 256) { cnt[i] = 0; rnk[i] = 0; }
    __syncthreads();
    int nD = min(gFillD[B], CAPE);
    for (int i = tid; i < nD; i += 256) atomicAdd(&cnt[partD[B * CAPE + i] & 511], 1);
    __syncthreads();
    if (tid < 64) {
        int bb = tid * 8, c8[8], mysum = 0;
#pragma unroll
        for (int j = 0; j < 8; ++j) { c8[j] = (cnt[bb + j] + 7) & ~7; mysum += c8[j]; }
        int incl = mysum;
#pragma unroll
        for (int off = 1; off < 64; off <<= 1) {
            int v = __shfl_up(incl, off);
            if (tid >= off) incl += v;
        }
        int run = incl - mysum;
#pragma unroll
        for (int j = 0; j < 8; ++j) { loc[bb + j] = run; run += c8[j]; }
    }
    __syncthreads();
    for (int n = tid; n < 512; n += 256) {
        int node = B * 512 + n;
        if (node < N_NODES) {
            int c = cnt[n], c8 = (c + 7) & ~7;
            meta[node] = make_int2(B * CAPC + loc[n], c);
            for (int e = c; e < c8; ++e) csr[B * CAPC + loc[n] + e] = (u32)DUMMY;
        }
    }
    for (int i = tid; i < nD; i += 256) {
        u32 p = partD[B * CAPE + i];
        int ln = p & 511;
        u32 s = p >> 9;
        int r = atomicAdd(&rnk[ln], 1);
        int pos = loc[ln] + r;
        if (pos < CAPC) csr[B * CAPC + pos] = s | (pack15(dis[s]) << 17);
    }
}

// ---------- SPMM gather: 8 nodes/wave, 8 lanes/node, lane = 8 features (dwordx4 row) ----------
// hi-plane-only output (lo planes of Tx1/Ty are numerically dead).
template <int J>
__device__ __forceinline__ void edge_step(u32 ent, const uint4* __restrict__ in4,
                                          int p, float* a) {
    u32 q = (u32)__builtin_amdgcn_ds_swizzle((int)ent, (J << 5) | 0x18);
    u32 s = q & 0x1FFFFu;
    float w = unpack15(q >> 17);           // pad entries: w bits = 0 -> exact no-op
    uint4 v = in4[((size_t)s << 3) + p];
    a[0] = fmaf(w, blo(v.x), a[0]);
    a[1] = fmaf(w, bhi(v.x), a[1]);
    a[2] = fmaf(w, blo(v.y), a[2]);
    a[3] = fmaf(w, bhi(v.y), a[3]);
    a[4] = fmaf(w, blo(v.z), a[4]);
    a[5] = fmaf(w, bhi(v.z), a[5]);
    a[6] = fmaf(w, blo(v.w), a[6]);
    a[7] = fmaf(w, bhi(v.w), a[7]);
}

#define SPMM_BLOCKS 3125   // 3125 blocks * 4 waves * 8 nodes = 100000 exactly

__global__ __launch_bounds__(256) void spmm(const u16* __restrict__ in,     // (N+1)x64 bf16
                                            const float* __restrict__ dis,
                                            const int2* __restrict__ meta,
                                            const u32* __restrict__ csr,
                                            u16* __restrict__ outhi) {
    const int tid = threadIdx.x;
    const int lane = tid & 63;
    const int gw = blockIdx.x * 4 + (tid >> 6);   // global wave id
    const int node = gw * 8 + (lane >> 3);        // 8 nodes per wave (exact fit)
    const int p = lane & 7;                        // feature chunk [8p, 8p+8)

    int2 mt = meta[node];
    int c8 = (mt.y + 7) & ~7;                      // list DUMMY-padded to x8
    const u32* lst = csr + mt.x;
    const uint4* in4 = (const uint4*)in;

    float a[8] = {0.f, 0.f, 0.f, 0.f, 0.f, 0.f, 0.f, 0.f};

    for (int e = 0; e < c8; e += 8) {
        u32 ent = lst[e + p];                      // lane p holds group's entry e+p
        edge_step<0>(ent, in4, p, a);
        edge_step<1>(ent, in4, p, a);
        edge_step<2>(ent, in4, p, a);
        edge_step<3>(ent, in4, p, a);
        edge_step<4>(ent, in4, p, a);
        edge_step<5>(ent, in4, p, a);
        edge_step<6>(ent, in4, p, a);
        edge_step<7>(ent, in4, p, a);
    }

    float vd = -dis[node];
    uint4 H;
    H.x = pk2(f2bf(vd * a[0]), f2bf(vd * a[1]));
    H.y = pk2(f2bf(vd * a[2]), f2bf(vd * a[3]));
    H.z = pk2(f2bf(vd * a[4]), f2bf(vd * a[5]));
    H.w = pk2(f2bf(vd * a[6]), f2bf(vd * a[7]));
    *((uint4*)((u32*)outhi + (((size_t)node << 5) + (p << 2)))) = H;
}

// ---------- dense via MFMA, split-bf16 A0 only, Chebyshev fold in the weights ----------
// out = A0@(W0 - W2) + A1@W1 + Ty@(2*W2);  A1/Ty bf16-only, A0 keeps a lo plane.
#define DGRID 1250
#define DNT 5              // 1250 * 5 * 16 = 100000 rows exactly
#define LSTR 200           // u16 per LDS row for Ah (192 data + 8 pad)
#define LSTR2 72           // u16 per LDS row for Al (64 data + 8 pad)

__device__ __forceinline__ float foldW(const float* __restrict__ W, int kk, int col,
                                       int ncols) {
    float wv = W[kk * ncols + col];
    if (kk < 64) wv -= W[(kk + 128) * ncols + col];   // W0 - W2
    else if (kk >= 128) wv += wv;                     // 2 * W2
    return wv;
}

__global__ __launch_bounds__(256) void dense1_mf(const float* __restrict__ x,
                                                 const u16* __restrict__ a1h,
                                                 const u16* __restrict__ tyh,
                                                 const float* __restrict__ W,
                                                 const float* __restrict__ bias,
                                                 u16* __restrict__ ohi,
                                                 u16* __restrict__ olo) {
    __shared__ u16 Ah[16 * LSTR], Al[16 * LSTR2];
    const int tid = threadIdx.x, wid = tid >> 6, lane = tid & 63;
    const int lrow = lane & 15, lk8 = (lane >> 4) * 8;
    const int col = wid * 16 + lrow;

    bf16x8 wh[6], wl[6];
#pragma unroll
    for (int c = 0; c < 6; ++c) {
        bf16x8 h, l;
#pragma unroll
        for (int i = 0; i < 8; ++i) {
            float wv = foldW(W, c * 32 + lk8 + i, col, 64);
            u16 hb_ = f2bf(wv);
            h[i] = (short)hb_;
            l[i] = (short)f2bf(wv - bf2f(hb_));
        }
        wh[c] = h; wl[c] = l;
    }
    float bv = bias[col];
    const int srow = tid >> 4, sc4 = (tid & 15) * 4;

    for (int t = 0; t < DNT; ++t) {
        int r0 = (blockIdx.x * DNT + t) * 16;
        size_t rb = ((size_t)(r0 + srow) << 6) + sc4;
        {
            float4 v = *(const float4*)&x[rb];
            const float* vp = (const float*)&v;
            ushort4 hv, lv;
#pragma unroll
            for (int i = 0; i < 4; ++i) {
                u16 hb_ = f2bf(vp[i]);
                ((u16*)&hv)[i] = hb_;
                ((u16*)&lv)[i] = f2bf(vp[i] - bf2f(hb_));
            }
            *(ushort4*)&Ah[srow * LSTR + sc4] = hv;
            *(ushort4*)&Al[srow * LSTR2 + sc4] = lv;
        }
        *(ushort4*)&Ah[srow * LSTR + 64 + sc4] = *(const ushort4*)&a1h[rb];
        *(ushort4*)&Ah[srow * LSTR + 128 + sc4] = *(const ushort4*)&tyh[rb];
        __syncthreads();

        f32x4 acc = {bv, bv, bv, bv};
#pragma unroll
        for (int c = 0; c < 6; ++c) {
            bf16x8 ah = *(const bf16x8*)&Ah[lrow * LSTR + c * 32 + lk8];
            acc = __builtin_amdgcn_mfma_f32_16x16x32_bf16(ah, wh[c], acc, 0, 0, 0);
            acc = __builtin_amdgcn_mfma_f32_16x16x32_bf16(ah, wl[c], acc, 0, 0, 0);
        }
#pragma unroll
        for (int c = 0; c < 2; ++c) {   // A0 lo plane covers k in [0,64)
            bf16x8 al = *(const bf16x8*)&Al[lrow * LSTR2 + c * 32 + lk8];
            acc = __builtin_amdgcn_mfma_f32_16x16x32_bf16(al, wh[c], acc, 0, 0, 0);
        }
        __syncthreads();

#pragma unroll
        for (int j = 0; j < 4; ++j) {
            int row = r0 + (lane >> 4) * 4 + j;
            float v = fmaxf(acc[j], 0.0f);
            u16 hb_ = f2bf(v);
            ohi[((size_t)row << 6) + col] = hb_;
            olo[((size_t)row << 6) + col] = f2bf(v - bf2f(hb_));
        }
    }
}

__global__ __launch_bounds__(256) void dense2_mf(const u16* __restrict__ a0h,
                                                 const u16* __restrict__ a0l,
                                                 const u16* __restrict__ a1h,
                                                 const u16* __restrict__ tyh,
                                                 const float* __restrict__ W,
                                                 const float* __restrict__ bias,
                                                 float* __restrict__ out) {
    __shared__ u16 Ah[16 * LSTR], Al[16 * LSTR2];
    __shared__ float Ls[16][48];
    const int tid = threadIdx.x, wid = tid >> 6, lane = tid & 63;
    const int lrow = lane & 15, lk8 = (lane >> 4) * 8;
    const int col = wid * 16 + lrow;
    const bool act = (wid < 3);
    const bool cok = act && (col < NCLS);

    bf16x8 wh[6], wl[6];
#pragma unroll
    for (int c = 0; c < 6; ++c) {
        bf16x8 h = 0, l = 0;
        if (cok) {
#pragma unroll
            for (int i = 0; i < 8; ++i) {
                float wv = foldW(W, c * 32 + lk8 + i, col, NCLS);
                u16 hb_ = f2bf(wv);
                h[i] = (short)hb_;
                l[i] = (short)f2bf(wv - bf2f(hb_));
            }
        }
        wh[c] = h; wl[c] = l;
    }
    float bv = cok ? bias[col] : 0.0f;
    const int srow = tid >> 4, sc4 = (tid & 15) * 4;

    for (int t = 0; t < DNT; ++t) {
        int r0 = (blockIdx.x * DNT + t) * 16;
        size_t rb = ((size_t)(r0 + srow) << 6) + sc4;
        *(ushort4*)&Ah[srow * LSTR + sc4] = *(const ushort4*)&a0h[rb];
        *(ushort4*)&Al[srow * LSTR2 + sc4] = *(const ushort4*)&a0l[rb];
        *(ushort4*)&Ah[srow * LSTR + 64 + sc4] = *(const ushort4*)&a1h[rb];
        *(ushort4*)&Ah[srow * LSTR + 128 + sc4] = *(const ushort4*)&tyh[rb];
        __syncthreads();

        if (act) {
            f32x4 acc = {bv, bv, bv, bv};
#pragma unroll
            for (int c = 0; c < 6; ++c) {
                bf16x8 ah = *(const bf16x8*)&Ah[lrow * LSTR + c * 32 + lk8];
                acc = __builtin_amdgcn_mfma_f32_16x16x32_bf16(ah, wh[c], acc, 0, 0, 0);
                acc = __builtin_amdgcn_mfma_f32_16x16x32_bf16(ah, wl[c], acc, 0, 0, 0);
            }
#pragma unroll
            for (int c = 0; c < 2; ++c) {
                bf16x8 al = *(const bf16x8*)&Al[lrow * LSTR2 + c * 32 + lk8];
                acc = __builtin_amdgcn_mfma_f32_16x16x32_bf16(al, wh[c], acc, 0, 0, 0);
            }
#pragma unroll
            for (int j = 0; j < 4; ++j) Ls[(lane >> 4) * 4 + j][col] = acc[j];
        }
        __syncthreads();

        {   // softmax: 16 rows, one 16-lane group per row (4 rows per wave)
            int row = wid * 4 + (lane >> 4);
            int cg = lane & 15;
            float v0 = Ls[row][cg];
            float v1 = Ls[row][cg + 16];
            float v2 = (cg < 8) ? Ls[row][cg + 32] : -1e30f;
            float m = fmaxf(fmaxf(v0, v1), v2);
#pragma unroll
            for (int o = 8; o; o >>= 1) m = fmaxf(m, __shfl_xor(m, o));
            float e0 = expf(v0 - m), e1 = expf(v1 - m);
            float e2 = (cg < 8) ? expf(v2 - m) : 0.0f;
            float s = e0 + e1 + e2;
#pragma unroll
            for (int o = 8; o; o >>= 1) s += __shfl_xor(s, o);
            float inv = 1.0f / s;
            size_t ob = (size_t)(r0 + row) * NCLS;
            out[ob + cg] = e0 * inv;
            out[ob + cg + 16] = e1 * inv;
            if (cg < 8) out[ob + cg + 32] = e2 * inv;
        }
    }
}

// ---------------- host ----------------

extern "C" void kernel_launch(void* const* d_in, const int* in_sizes, int n_in,
                              void* d_out, int out_size, void* d_ws, size_t ws_size,
                              hipStream_t stream) {
    const float* x = (const float*)d_in[0];
    const int* edge_index = (const int*)d_in[1];
    const float* W1 = (const float*)d_in[2];
    const float* b1 = (const float*)d_in[3];
    const float* W2 = (const float*)d_in[4];
    const float* b2 = (const float*)d_in[5];
    float* out = (float*)d_out;

    const int* src = edge_index;
    const int* dst = edge_index + N_EDGES;

    char* ws = (char*)d_ws;
    size_t off = 0;
    auto carve = [&](size_t bytes) -> void* {
        void* p = ws + off;
        off = align256(off + bytes);
        return p;
    };
    int* gFillD = (int*)carve((size_t)NBUCK * 4);
    int* gFillS = (int*)carve((size_t)NBUCK * 4);
    size_t zero_bytes = off;
    u32* partD = (u32*)carve((size_t)NBUCK * CAPE * 4);     // 7.0 MB ((s<<9)|dlocal)
    u16* partS = (u16*)carve((size_t)NBUCK * CAPE * 2);     // 3.5 MB (bucket-local src)
    u32* csr = (u32*)carve((size_t)NBUCK * CAPC * 4 + 1024);// 8.4 MB (src|w15<<17)
    int2* meta = (int2*)carve((size_t)N_NODES * 8);         // 0.8 MB
    float* dis = (float*)carve((size_t)(N_NODES + 1) * 4);  // 0.4 MB
    const size_t FB = (size_t)(N_NODES + 1) * 64 * 2;       // 12.8 MB per bf16 plane
    u16* xb  = (u16*)carve(FB);
    u16* t1h = (u16*)carve(FB);   // Tx1 / Th1 hi (bf16-only)
    u16* tyh = (u16*)carve(FB);   // L.Tx1 / L.Th1 hi (bf16-only)
    u16* hh  = (u16*)carve(FB);   // h hi (gather input for layer 2)
    u16* hl  = (u16*)carve(FB);   // h lo (dense2 A0 lo plane)
    // total ~84 MB

    (void)hipMemsetAsync(d_ws, 0, zero_bytes, stream);   // gFillD/gFillS only (1.6 KB)

    pscatter_conv<<<PS_BLOCKS + CONV_BLOCKS, 256, 0, stream>>>(src, dst, gFillD, gFillS,
                                                               partD, partS, x, xb);
    build_dis<<<NBUCK, 256, 0, stream>>>(partS, gFillS, dis);
    build_csr<<<NBUCK, 256, 0, stream>>>(partD, gFillD, dis, csr, meta);

    // layer 1: Tx1 = L.x ; Ty = L.Tx1 ; h = relu(x@(W0-W2) + Tx1@W1 + Ty@2W2 + b1)
    spmm<<<SPMM_BLOCKS, 256, 0, stream>>>(xb, dis, meta, csr, t1h);
    spmm<<<SPMM_BLOCKS, 256, 0, stream>>>(t1h, dis, meta, csr, tyh);
    dense1_mf<<<DGRID, 256, 0, stream>>>(x, t1h, tyh, W1, b1, hh, hl);

    // layer 2 (t1h/tyh reused)
    spmm<<<SPMM_BLOCKS, 256, 0, stream>>>(hh, dis, meta, csr, t1h);
    spmm<<<SPMM_BLOCKS, 256, 0, stream>>>(t1h, dis, meta, csr, tyh);
    dense2_mf<<<DGRID, 256, 0, stream>>>(hh, hl, t1h, tyh, W2, b2, out);
}